// Round 1
// baseline (8343.922 us; speedup 1.0000x reference)
//
#include <hip/hip_runtime.h>

// VoxelNet: scatter-mean -> conv3d(4->64)+BN+ReLU -> conv3d(64->64)+BN+ReLU
//           -> height-pool reshape -> 1x1 conv (256->256), batch=2 identical.
// Strategy: compute at B=1 (batch slots identical; BN stats unchanged),
// duplicate output at the end. Intermediates live inside d_out (each half
// is exactly 64*160000 floats); ws holds only the 2.56MB dense grid + BN coefs.

#define VN   40000
#define CIN  4
#define PN   32
#define DDIM 4
#define HDIM 200
#define WDIM 200
#define SP2  40000      // H*W
#define SP3  160000     // D*H*W
#define HID  64
#define OUTC 256
#define EPSF 1e-5f

// ---- scatter-mean: voxels [V,4,32] -> grid [4,4,200,200] ----
__global__ __launch_bounds__(256) void k_scatter(const float* __restrict__ vox,
                                                 const int* __restrict__ idx,
                                                 float* __restrict__ grid) {
    int t = blockIdx.x * 256 + threadIdx.x;
    if (t >= VN * CIN) return;
    int v = t >> 2, c = t & 3;
    const float4* p = reinterpret_cast<const float4*>(vox + (size_t)(v * CIN + c) * PN);
    float s = 0.f;
#pragma unroll
    for (int i = 0; i < PN / 4; ++i) {
        float4 q = p[i];
        s += (q.x + q.y) + (q.z + q.w);
    }
    int x = idx[v * 3 + 0], y = idx[v * 3 + 1], z = idx[v * 3 + 2];
    grid[c * SP3 + z * SP2 + y * WDIM + x] = s * (1.f / PN);
}

// ---- conv1: 3x3x3 SAME, 4 -> 64, + bias ----
__global__ __launch_bounds__(256) void k_conv1(const float* __restrict__ X,
                                               const float* __restrict__ W1,
                                               const float* __restrict__ B1,
                                               float* __restrict__ Y) {
    int s = blockIdx.x * 256 + threadIdx.x;   // SP3 = 625*256 exactly
    int co = blockIdx.y;
    int d = s / SP2, r = s % SP2, h = r / WDIM, w = r % WDIM;
    float acc = B1[co];
#pragma unroll
    for (int ci = 0; ci < CIN; ++ci) {
        const float* xb = X + ci * SP3;
        const float* wb = W1 + (co * CIN + ci) * 27;
#pragma unroll
        for (int kd = 0; kd < 3; ++kd) {
            int dd = d + kd - 1;
            if ((unsigned)dd >= DDIM) continue;
#pragma unroll
            for (int kh = 0; kh < 3; ++kh) {
                int hh = h + kh - 1;
                if ((unsigned)hh >= HDIM) continue;
                const float* xr = xb + dd * SP2 + hh * WDIM;
#pragma unroll
                for (int kw = 0; kw < 3; ++kw) {
                    int ww = w + kw - 1;
                    if ((unsigned)ww >= WDIM) continue;
                    acc = fmaf(xr[ww], wb[kd * 9 + kh * 3 + kw], acc);
                }
            }
        }
    }
    Y[co * SP3 + s] = acc;
}

// ---- per-channel BN stats -> a = g*rsqrt(var+eps), b = be - mean*a ----
__global__ __launch_bounds__(512) void k_stats(const float* __restrict__ Y,
                                               const float* __restrict__ G,
                                               const float* __restrict__ BE,
                                               float* __restrict__ AB, int nch) {
    int c = blockIdx.x;
    const float4* p = reinterpret_cast<const float4*>(Y + (size_t)c * SP3);
    float s = 0.f, s2 = 0.f;
    for (int i = threadIdx.x; i < SP3 / 4; i += 512) {
        float4 v = p[i];
        s  += (v.x + v.y) + (v.z + v.w);
        s2 += (v.x * v.x + v.y * v.y) + (v.z * v.z + v.w * v.w);
    }
    __shared__ float rs[512], rq[512];
    rs[threadIdx.x] = s; rq[threadIdx.x] = s2;
    __syncthreads();
    for (int off = 256; off > 0; off >>= 1) {
        if (threadIdx.x < off) {
            rs[threadIdx.x] += rs[threadIdx.x + off];
            rq[threadIdx.x] += rq[threadIdx.x + off];
        }
        __syncthreads();
    }
    if (threadIdx.x == 0) {
        float mean = rs[0] * (1.f / SP3);
        float var  = rq[0] * (1.f / SP3) - mean * mean;
        float a = G[c] * rsqrtf(var + EPSF);
        AB[c] = a;
        AB[nch + c] = BE[c] - mean * a;
    }
}

// ---- elementwise BN+ReLU in place (vectorized float4) ----
__global__ __launch_bounds__(256) void k_bnrelu(float* __restrict__ Y,
                                                const float* __restrict__ AB) {
    int i = blockIdx.x * 256 + threadIdx.x;    // HID*SP3/4 = 2,560,000 exact
    int c = i / (SP3 / 4);
    float a = AB[c], b = AB[HID + c];
    float4* p = reinterpret_cast<float4*>(Y);
    float4 v = p[i];
    v.x = fmaxf(fmaf(a, v.x, b), 0.f);
    v.y = fmaxf(fmaf(a, v.y, b), 0.f);
    v.z = fmaxf(fmaf(a, v.z, b), 0.f);
    v.w = fmaxf(fmaf(a, v.w, b), 0.f);
    p[i] = v;
}

// ---- conv2: 3x3x3 SAME, 64 -> 64, + bias; weights staged in LDS ----
__global__ __launch_bounds__(256) void k_conv2(const float* __restrict__ X,
                                               const float* __restrict__ W2,
                                               const float* __restrict__ B2,
                                               float* __restrict__ Y) {
    __shared__ float wl[HID * 27];   // 1728 floats = 6.9 KB
    int co = blockIdx.y;
    for (int i = threadIdx.x; i < HID * 27; i += 256)
        wl[i] = W2[co * HID * 27 + i];
    __syncthreads();
    int s = blockIdx.x * 256 + threadIdx.x;   // exact
    int d = s / SP2, r = s % SP2, h = r / WDIM, w = r % WDIM;
    float acc = B2[co];
    for (int ci = 0; ci < HID; ++ci) {
        const float* xb = X + ci * SP3;
        const float* wb = wl + ci * 27;
#pragma unroll
        for (int kd = 0; kd < 3; ++kd) {
            int dd = d + kd - 1;
            if ((unsigned)dd >= DDIM) continue;
#pragma unroll
            for (int kh = 0; kh < 3; ++kh) {
                int hh = h + kh - 1;
                if ((unsigned)hh >= HDIM) continue;
                const float* xr = xb + dd * SP2 + hh * WDIM;
#pragma unroll
                for (int kw = 0; kw < 3; ++kw) {
                    int ww = w + kw - 1;
                    if ((unsigned)ww >= WDIM) continue;
                    acc = fmaf(xr[ww], wb[kd * 9 + kh * 3 + kw], acc);
                }
            }
        }
    }
    Y[co * SP3 + s] = acc;
}

// ---- head: 1x1 conv [256 x 40000] = WH[256,256] * X[256,40000] + bh ----
// Writes batch-0 half of d_out only (reads X from upper half of d_out).
__global__ __launch_bounds__(256) void k_head(const float* __restrict__ X,
                                              const float* __restrict__ WH,
                                              const float* __restrict__ BH,
                                              float* __restrict__ O) {
    __shared__ float wl[4 * 256];
    int og = blockIdx.y;             // 64 groups of 4 output channels
    for (int i = threadIdx.x; i < 4 * 256; i += 256)
        wl[i] = WH[og * 4 * 256 + i];
    __syncthreads();
    int s = blockIdx.x * 256 + threadIdx.x;
    int o = og * 4;
    if (s >= SP2) return;
    float a0 = BH[o], a1 = BH[o + 1], a2 = BH[o + 2], a3 = BH[o + 3];
    for (int k = 0; k < 256; ++k) {
        float xv = X[k * SP2 + s];
        a0 = fmaf(wl[k],       xv, a0);
        a1 = fmaf(wl[256 + k], xv, a1);
        a2 = fmaf(wl[512 + k], xv, a2);
        a3 = fmaf(wl[768 + k], xv, a3);
    }
    O[(o + 0) * SP2 + s] = a0;
    O[(o + 1) * SP2 + s] = a1;
    O[(o + 2) * SP2 + s] = a2;
    O[(o + 3) * SP2 + s] = a3;
}

// ---- duplicate batch 0 -> batch 1 (overwrites the scratch upper half) ----
__global__ __launch_bounds__(256) void k_dup(float* __restrict__ O) {
    int i = blockIdx.x * 256 + threadIdx.x;   // OUTC*SP2/4 = 2,560,000 exact
    float4* p = reinterpret_cast<float4*>(O);
    p[OUTC * SP2 / 4 + i] = p[i];
}

extern "C" void kernel_launch(void* const* d_in, const int* in_sizes, int n_in,
                              void* d_out, int out_size, void* d_ws, size_t ws_size,
                              hipStream_t stream) {
    const float* vox = (const float*)d_in[0];
    const int*   idx = (const int*)d_in[1];
    const float* w1  = (const float*)d_in[3];
    const float* b1  = (const float*)d_in[4];
    const float* g1  = (const float*)d_in[5];
    const float* be1 = (const float*)d_in[6];
    const float* w2  = (const float*)d_in[7];
    const float* b2  = (const float*)d_in[8];
    const float* g2  = (const float*)d_in[9];
    const float* be2 = (const float*)d_in[10];
    const float* wh  = (const float*)d_in[11];
    const float* bh  = (const float*)d_in[12];

    float* out  = (float*)d_out;
    float* grid = (float*)d_ws;              // 640,000 floats
    float* ab1  = grid + CIN * SP3;          // 128 floats
    float* ab2  = ab1 + 2 * HID;             // 128 floats
    float* y1   = out;                       // lower half of d_out (10,240,000 f)
    float* y2   = out + HID * SP3;           // upper half of d_out

    hipMemsetAsync(grid, 0, CIN * SP3 * sizeof(float), stream);
    k_scatter<<<(VN * CIN + 255) / 256, 256, 0, stream>>>(vox, idx, grid);
    k_conv1<<<dim3(SP3 / 256, HID), 256, 0, stream>>>(grid, w1, b1, y1);
    k_stats<<<HID, 512, 0, stream>>>(y1, g1, be1, ab1, HID);
    k_bnrelu<<<HID * SP3 / 4 / 256, 256, 0, stream>>>(y1, ab1);
    k_conv2<<<dim3(SP3 / 256, HID), 256, 0, stream>>>(y1, w2, b2, y2);
    k_stats<<<HID, 512, 0, stream>>>(y2, g2, be2, ab2, HID);
    k_bnrelu<<<HID * SP3 / 4 / 256, 256, 0, stream>>>(y2, ab2);
    k_head<<<dim3((SP2 + 255) / 256, OUTC / 4), 256, 0, stream>>>(y2, wh, bh, out);
    k_dup<<<OUTC * SP2 / 4 / 256, 256, 0, stream>>>(out);
}

// Round 2
// 442.623 us; speedup vs baseline: 18.8511x; 18.8511x over previous
//
#include <hip/hip_runtime.h>

// VoxelNet on MI355X. Batch collapsed to 1 (identical slots; BN stats invariant).
// conv2 + head are bf16 implicit-GEMM on MFMA (16x16x32), fp32 accumulate.
// Layouts: y1 fp32 [ci][sp3]; xT bf16 [sp3][64ci]; y2 bf16 [sp3][64co].

#define VN   40000
#define CIN  4
#define PN   32
#define SP2  40000
#define SP3  160000
#define HID  64
#define OUTC 256
#define EPSF 1e-5f

typedef __attribute__((ext_vector_type(8))) short short8;
typedef __attribute__((ext_vector_type(4))) float f32x4;

__device__ inline unsigned short f2bf(float f) {
    unsigned u = __builtin_bit_cast(unsigned, f);
    return (unsigned short)((u + 0x7fffu + ((u >> 16) & 1u)) >> 16);
}
__device__ inline float bf2f(unsigned short h) {
    return __builtin_bit_cast(float, ((unsigned)h) << 16);
}

// ---- scatter-mean ----
__global__ __launch_bounds__(256) void k_scatter(const float* __restrict__ vox,
                                                 const int* __restrict__ idx,
                                                 float* __restrict__ grid) {
    int t = blockIdx.x * 256 + threadIdx.x;
    if (t >= VN * CIN) return;
    int v = t >> 2, c = t & 3;
    const float4* p = reinterpret_cast<const float4*>(vox + (size_t)(v * CIN + c) * PN);
    float s = 0.f;
#pragma unroll
    for (int i = 0; i < PN / 4; ++i) { float4 q = p[i]; s += (q.x + q.y) + (q.z + q.w); }
    int x = idx[v * 3 + 0], y = idx[v * 3 + 1], z = idx[v * 3 + 2];
    grid[c * SP3 + z * SP2 + y * 200 + x] = s * (1.f / PN);
}

// ---- conv1: 3x3x3, 4->64 fp32 (input is L2-resident; fine for now) ----
__global__ __launch_bounds__(256) void k_conv1(const float* __restrict__ X,
                                               const float* __restrict__ W1,
                                               const float* __restrict__ B1,
                                               float* __restrict__ Y) {
    int s = blockIdx.x * 256 + threadIdx.x;
    int co = blockIdx.y;
    int d = s / SP2, r = s % SP2, h = r / 200, w = r % 200;
    float acc = B1[co];
#pragma unroll
    for (int ci = 0; ci < CIN; ++ci) {
        const float* xb = X + ci * SP3;
        const float* wb = W1 + (co * CIN + ci) * 27;
#pragma unroll
        for (int kd = 0; kd < 3; ++kd) {
            int dd = d + kd - 1; if ((unsigned)dd >= 4) continue;
#pragma unroll
            for (int kh = 0; kh < 3; ++kh) {
                int hh = h + kh - 1; if ((unsigned)hh >= 200) continue;
                const float* xr = xb + dd * SP2 + hh * 200;
#pragma unroll
                for (int kw = 0; kw < 3; ++kw) {
                    int ww = w + kw - 1; if ((unsigned)ww >= 200) continue;
                    acc = fmaf(xr[ww], wb[kd * 9 + kh * 3 + kw], acc);
                }
            }
        }
    }
    Y[co * SP3 + s] = acc;
}

// ---- BN stats for fp32 [c][sp] layout (layer 1) ----
__global__ __launch_bounds__(512) void k_stats(const float* __restrict__ Y,
                                               const float* __restrict__ G,
                                               const float* __restrict__ BE,
                                               float* __restrict__ AB, int nch) {
    int c = blockIdx.x;
    const float4* p = reinterpret_cast<const float4*>(Y + (size_t)c * SP3);
    float s = 0.f, s2 = 0.f;
    for (int i = threadIdx.x; i < SP3 / 4; i += 512) {
        float4 v = p[i];
        s += (v.x + v.y) + (v.z + v.w);
        s2 += (v.x * v.x + v.y * v.y) + (v.z * v.z + v.w * v.w);
    }
    __shared__ float rs[512], rq[512];
    rs[threadIdx.x] = s; rq[threadIdx.x] = s2;
    __syncthreads();
    for (int off = 256; off > 0; off >>= 1) {
        if (threadIdx.x < off) { rs[threadIdx.x] += rs[threadIdx.x + off]; rq[threadIdx.x] += rq[threadIdx.x + off]; }
        __syncthreads();
    }
    if (threadIdx.x == 0) {
        float mean = rs[0] * (1.f / SP3);
        float var  = rq[0] * (1.f / SP3) - mean * mean;
        float a = G[c] * rsqrtf(var + EPSF);
        AB[c] = a; AB[nch + c] = BE[c] - mean * a;
    }
}

// ---- BN+ReLU + transpose + bf16: y1 [c][sp] fp32 -> xT [sp][64c] bf16 ----
__global__ __launch_bounds__(256) void k_bnrelu_t(const float* __restrict__ Y,
                                                  const float* __restrict__ AB,
                                                  unsigned short* __restrict__ XT) {
    __shared__ unsigned short tile[64][72];
    int sp0 = blockIdx.x * 64;
    int t = threadIdx.x;
    int c = t >> 2, q = t & 3;
    float a = AB[c], b = AB[64 + c];
    const float4* src = reinterpret_cast<const float4*>(Y + (size_t)c * SP3 + sp0);
#pragma unroll
    for (int k = 0; k < 4; ++k) {
        float4 v = src[q + k * 4];
        int spl = (q + k * 4) * 4;
        tile[spl + 0][c] = f2bf(fmaxf(fmaf(a, v.x, b), 0.f));
        tile[spl + 1][c] = f2bf(fmaxf(fmaf(a, v.y, b), 0.f));
        tile[spl + 2][c] = f2bf(fmaxf(fmaf(a, v.z, b), 0.f));
        tile[spl + 3][c] = f2bf(fmaxf(fmaf(a, v.w, b), 0.f));
    }
    __syncthreads();
#pragma unroll
    for (int it = 0; it < 2; ++it) {
        int s = t + it * 256;
        int row = s >> 3, sl = s & 7;
        uint4 v = *reinterpret_cast<uint4*>(&tile[row][sl * 8]);
        *reinterpret_cast<uint4*>(XT + (size_t)(sp0 + row) * 64 + sl * 8) = v;
    }
}

// ---- pack conv2 weights into A-fragment layout: [tap][cib][mt][lane][8] bf16 ----
__global__ void k_packA2(const float* __restrict__ W2, unsigned short* __restrict__ A) {
    int i = blockIdx.x * 256 + threadIdx.x;
    if (i >= 27 * 2 * 4 * 64 * 8) return;
    int j = i & 7, l = (i >> 3) & 63, mt = (i >> 9) & 3, cib = (i >> 11) & 1, tap = i >> 12;
    int co = mt * 16 + (l & 15);
    int ci = cib * 32 + (l >> 4) * 8 + j;
    A[i] = f2bf(W2[(co * 64 + ci) * 27 + tap]);
}

// ---- pack head weights: k' = d*64+hid; [cib8][mt16][lane][8] bf16 ----
__global__ void k_packAh(const float* __restrict__ WH, unsigned short* __restrict__ A) {
    int i = blockIdx.x * 256 + threadIdx.x;
    if (i >= 8 * 16 * 64 * 8) return;
    int j = i & 7, l = (i >> 3) & 63, mt = (i >> 9) & 15, cib = i >> 13;
    int o = mt * 16 + (l & 15);
    int kp = cib * 32 + (l >> 4) * 8 + j;
    int hid = kp & 63, d = kp >> 6;
    A[i] = f2bf(WH[o * 256 + hid * 4 + d]);
}

// ---- conv2 MFMA: xT bf16 [sp][64ci] -> y2 bf16 [sp][64co] ----
// Block: 8h x 8w tile, 4 waves (one d-plane each), window [4d][10h][10w][64ci]+pad.
__global__ __launch_bounds__(256) void k_conv2m(const unsigned short* __restrict__ XT,
                                                const unsigned short* __restrict__ A2,
                                                const float* __restrict__ B2,
                                                unsigned short* __restrict__ Y2) {
    __shared__ unsigned short win[400 * 72];   // 144B rows (128 data + 16 pad)
    int bh = blockIdx.x / 25, bw = blockIdx.x % 25;
    int h0 = bh * 8, w0 = bw * 8;
    int t = threadIdx.x;
    for (int e = t; e < 3200; e += 256) {
        int cell = e >> 3, sl = e & 7;
        int p = cell / 100, rr = cell % 100;
        int hh = rr / 10, ww = rr % 10;
        int hg = h0 + hh - 1, wg = w0 + ww - 1;
        uint4 v = make_uint4(0, 0, 0, 0);
        if ((unsigned)hg < 200u && (unsigned)wg < 200u)
            v = *reinterpret_cast<const uint4*>(XT + (size_t)(p * SP2 + hg * 200 + wg) * 64 + sl * 8);
        *reinterpret_cast<uint4*>(win + cell * 72 + sl * 8) = v;
    }
    __syncthreads();
    int wv = t >> 6, l = t & 63;
    int d = wv, ks = l >> 4, hq = (l >> 3) & 1, wq = l & 7;
    f32x4 acc[4][4] = {};
    for (int kd = 0; kd < 3; ++kd) {
        int p = d + kd - 1;
        if ((unsigned)p >= 4u) continue;
#pragma unroll
        for (int khw = 0; khw < 9; ++khw) {
            int kh = khw / 3, kw = khw % 3;
            int tap = kd * 9 + khw;
#pragma unroll
            for (int cib = 0; cib < 2; ++cib) {
                const uint4* ap = reinterpret_cast<const uint4*>(A2) + ((tap * 2 + cib) * 4) * 64 + l;
                short8 afr[4];
#pragma unroll
                for (int mt = 0; mt < 4; ++mt) afr[mt] = __builtin_bit_cast(short8, ap[mt * 64]);
#pragma unroll
                for (int nt = 0; nt < 4; ++nt) {
                    int cell = (p * 10 + nt * 2 + hq + kh) * 10 + (wq + kw);
                    short8 bfr = *reinterpret_cast<const short8*>(win + cell * 72 + cib * 32 + ks * 8);
#pragma unroll
                    for (int mt = 0; mt < 4; ++mt)
                        acc[mt][nt] = __builtin_amdgcn_mfma_f32_16x16x32_bf16(afr[mt], bfr, acc[mt][nt], 0, 0, 0);
                }
            }
        }
    }
#pragma unroll
    for (int mt = 0; mt < 4; ++mt) {
        int co0 = mt * 16 + ks * 4;
        float b0 = B2[co0], b1 = B2[co0 + 1], b2 = B2[co0 + 2], b3 = B2[co0 + 3];
#pragma unroll
        for (int nt = 0; nt < 4; ++nt) {
            int sp = d * SP2 + (h0 + nt * 2 + hq) * 200 + (w0 + wq);
            uint2 o;
            o.x = (unsigned)f2bf(acc[mt][nt][0] + b0) | ((unsigned)f2bf(acc[mt][nt][1] + b1) << 16);
            o.y = (unsigned)f2bf(acc[mt][nt][2] + b2) | ((unsigned)f2bf(acc[mt][nt][3] + b3) << 16);
            *reinterpret_cast<uint2*>(Y2 + (size_t)sp * 64 + co0) = o;
        }
    }
}

// ---- stats pass 1 over y2 bf16 [sp][64]: per-block partial sums ----
__global__ __launch_bounds__(256) void k_stats2p(const unsigned short* __restrict__ Y2,
                                                 float* __restrict__ P) {
    int bid = blockIdx.x, t = threadIdx.x, wv = t >> 6, l = t & 63;
    float s = 0.f, q = 0.f;
    int r0 = bid * 625, r1 = r0 + 625;
    for (int r = r0 + wv; r < r1; r += 4) {
        float v = bf2f(Y2[(size_t)r * 64 + l]);
        s += v; q += v * v;
    }
    __shared__ float ls[4][64], lq[4][64];
    ls[wv][l] = s; lq[wv][l] = q;
    __syncthreads();
    if (t < 64) {
        P[bid * 128 + t]      = ls[0][t] + ls[1][t] + ls[2][t] + ls[3][t];
        P[bid * 128 + 64 + t] = lq[0][t] + lq[1][t] + lq[2][t] + lq[3][t];
    }
}

__global__ void k_stats2f(const float* __restrict__ P, const float* __restrict__ G,
                          const float* __restrict__ BE, float* __restrict__ AB) {
    int c = threadIdx.x;  // 64
    float S = 0.f, Q = 0.f;
    for (int b = 0; b < 256; ++b) { S += P[b * 128 + c]; Q += P[b * 128 + 64 + c]; }
    float m = S * (1.f / SP3), var = Q * (1.f / SP3) - m * m;
    float a = G[c] * rsqrtf(var + EPSF);
    AB[c] = a; AB[64 + c] = BE[c] - m * a;
}

// ---- BN+ReLU in place on y2 bf16 ----
__global__ __launch_bounds__(256) void k_bnrelu2(unsigned short* __restrict__ Y2,
                                                 const float* __restrict__ AB) {
    int i = blockIdx.x * 256 + threadIdx.x;     // 1.28M threads, 8 elems each
    int co0 = (i * 8) & 63;
    uint4 v = *reinterpret_cast<uint4*>(Y2 + (size_t)i * 8);
    unsigned r[4]; r[0] = v.x; r[1] = v.y; r[2] = v.z; r[3] = v.w;
#pragma unroll
    for (int k = 0; k < 4; ++k) {
        float lo = bf2f((unsigned short)(r[k] & 0xffff));
        float hi = bf2f((unsigned short)(r[k] >> 16));
        int c = co0 + k * 2;
        lo = fmaxf(fmaf(AB[c], lo, AB[64 + c]), 0.f);
        hi = fmaxf(fmaf(AB[c + 1], hi, AB[64 + c + 1]), 0.f);
        r[k] = (unsigned)f2bf(lo) | ((unsigned)f2bf(hi) << 16);
    }
    v.x = r[0]; v.y = r[1]; v.z = r[2]; v.w = r[3];
    *reinterpret_cast<uint4*>(Y2 + (size_t)i * 8) = v;
}

// ---- head MFMA: y2bf [sp][64] (k'=d*64+hid) x AH -> out fp32 [256][40000] ----
__global__ __launch_bounds__(256) void k_headm(const unsigned short* __restrict__ X,
                                               const unsigned short* __restrict__ AH,
                                               const float* __restrict__ BH,
                                               float* __restrict__ O) {
    int s0 = blockIdx.x * 16;
    int t = threadIdx.x, wv = t >> 6, l = t & 63;
    int ks = l >> 4, n = l & 15;
    f32x4 acc[4] = {};
#pragma unroll
    for (int cib = 0; cib < 8; ++cib) {
        int d = cib >> 1, hid0 = (cib & 1) * 32 + ks * 8;
        short8 bfr = *reinterpret_cast<const short8*>(X + (size_t)(d * SP2 + s0 + n) * 64 + hid0);
        const uint4* ap = reinterpret_cast<const uint4*>(AH) + (cib * 16 + wv * 4) * 64 + l;
#pragma unroll
        for (int mtl = 0; mtl < 4; ++mtl) {
            short8 afr = __builtin_bit_cast(short8, ap[mtl * 64]);
            acc[mtl] = __builtin_amdgcn_mfma_f32_16x16x32_bf16(afr, bfr, acc[mtl], 0, 0, 0);
        }
    }
#pragma unroll
    for (int mtl = 0; mtl < 4; ++mtl) {
        int o0 = (wv * 4 + mtl) * 16 + ks * 4;
        int sp = s0 + n;
#pragma unroll
        for (int r = 0; r < 4; ++r)
            O[(size_t)(o0 + r) * SP2 + sp] = acc[mtl][r] + BH[o0 + r];
    }
}

__global__ __launch_bounds__(256) void k_dup(float* __restrict__ O) {
    int i = blockIdx.x * 256 + threadIdx.x;
    float4* p = reinterpret_cast<float4*>(O);
    p[OUTC * SP2 / 4 + i] = p[i];
}

extern "C" void kernel_launch(void* const* d_in, const int* in_sizes, int n_in,
                              void* d_out, int out_size, void* d_ws, size_t ws_size,
                              hipStream_t stream) {
    const float* vox = (const float*)d_in[0];
    const int*   idx = (const int*)d_in[1];
    const float* w1  = (const float*)d_in[3];
    const float* b1  = (const float*)d_in[4];
    const float* g1  = (const float*)d_in[5];
    const float* be1 = (const float*)d_in[6];
    const float* w2  = (const float*)d_in[7];
    const float* b2  = (const float*)d_in[8];
    const float* g2  = (const float*)d_in[9];
    const float* be2 = (const float*)d_in[10];
    const float* wh  = (const float*)d_in[11];
    const float* bh  = (const float*)d_in[12];

    float* out  = (float*)d_out;
    float* grid = (float*)d_ws;                        // 640000 f
    float* ab1  = grid + CIN * SP3;                    // 128 f
    float* ab2  = ab1 + 128;                           // 128 f
    float* part = ab2 + 128;                           // 32768 f
    unsigned short* apack2 = (unsigned short*)(part + 32768);   // 110592 bf16
    unsigned short* apackh = apack2 + 110592;                   // 65536 bf16

    float* y1 = out;                                   // fp32 [64][160000]
    unsigned short* xT  = (unsigned short*)(out + 10240000);    // bf16 [160000][64]
    unsigned short* y2b = xT + 10240000;                        // bf16 [160000][64]

    hipMemsetAsync(grid, 0, CIN * SP3 * sizeof(float), stream);
    k_scatter<<<(VN * CIN + 255) / 256, 256, 0, stream>>>(vox, idx, grid);
    k_packA2<<<432, 256, 0, stream>>>(w2, apack2);
    k_packAh<<<256, 256, 0, stream>>>(wh, apackh);
    k_conv1<<<dim3(SP3 / 256, HID), 256, 0, stream>>>(grid, w1, b1, y1);
    k_stats<<<HID, 512, 0, stream>>>(y1, g1, be1, ab1, HID);
    k_bnrelu_t<<<2500, 256, 0, stream>>>(y1, ab1, xT);
    k_conv2m<<<625, 256, 0, stream>>>(xT, apack2, b2, y2b);
    k_stats2p<<<256, 256, 0, stream>>>(y2b, part);
    k_stats2f<<<1, 64, 0, stream>>>(part, g2, be2, ab2);
    k_bnrelu2<<<5000, 256, 0, stream>>>(y2b, ab2);
    k_headm<<<2500, 256, 0, stream>>>(y2b, apackh, bh, out);
    k_dup<<<10000, 256, 0, stream>>>(out);
}

// Round 3
// 244.694 us; speedup vs baseline: 34.0994x; 1.8089x over previous
//
#include <hip/hip_runtime.h>

// VoxelNet on MI355X. Batch collapsed to 1 (identical slots; BN stats invariant).
// All three matmul-shaped stages (conv1, conv2, head) are bf16 MFMA 16x16x32,
// fp32 accumulate. Activations live in channel-minor bf16 layout [sp][C]:
//   grid8 bf16 [sp3][8ci]  (ci 4..7 zero-padded)  -- in ws
//   y1b   bf16 [sp3][64]   -- upper half of d_out
//   y2b   bf16 [sp3][64]   -- upper half of d_out (after y1b)
// Head writes batch0 (lower half); k_dup copies to batch1 afterwards
// (must be separate: batch1 region aliases y1b/y2b scratch).

#define VN   40000
#define CIN  4
#define PN   32
#define SP2  40000
#define SP3  160000
#define HID  64
#define OUTC 256
#define EPSF 1e-5f

typedef __attribute__((ext_vector_type(8))) short short8;
typedef __attribute__((ext_vector_type(4))) float f32x4;

__device__ inline unsigned short f2bf(float f) {
    unsigned u = __builtin_bit_cast(unsigned, f);
    return (unsigned short)((u + 0x7fffu + ((u >> 16) & 1u)) >> 16);
}
__device__ inline float bf2f(unsigned short h) {
    return __builtin_bit_cast(float, ((unsigned)h) << 16);
}

// ---- scatter-mean: one thread per voxel -> grid8 bf16 [sp][8ci] ----
__global__ __launch_bounds__(256) void k_scatter(const float* __restrict__ vox,
                                                 const int* __restrict__ idx,
                                                 unsigned short* __restrict__ G8) {
    int v = blockIdx.x * 256 + threadIdx.x;
    if (v >= VN) return;
    const float4* p = reinterpret_cast<const float4*>(vox + (size_t)v * CIN * PN);
    float m[4];
#pragma unroll
    for (int c = 0; c < 4; ++c) {
        float s = 0.f;
#pragma unroll
        for (int i = 0; i < PN / 4; ++i) {
            float4 q = p[c * (PN / 4) + i];
            s += (q.x + q.y) + (q.z + q.w);
        }
        m[c] = s * (1.f / PN);
    }
    int x = idx[v * 3 + 0], y = idx[v * 3 + 1], z = idx[v * 3 + 2];
    size_t sp = (size_t)z * SP2 + y * 200 + x;
    uint2 o;
    o.x = (unsigned)f2bf(m[0]) | ((unsigned)f2bf(m[1]) << 16);
    o.y = (unsigned)f2bf(m[2]) | ((unsigned)f2bf(m[3]) << 16);
    *reinterpret_cast<uint2*>(G8 + sp * 8) = o;   // ci 4..7 stay zero (memset)
}

// ---- pack conv1 weights: k = tap*8+ci8 (28 taps, ci padded to 8), 7 slices ----
__global__ void k_packA1(const float* __restrict__ W1, unsigned short* __restrict__ A) {
    int i = blockIdx.x * 256 + threadIdx.x;
    if (i >= 7 * 4 * 64 * 8) return;
    int j = i & 7, l = (i >> 3) & 63, mt = (i >> 9) & 3, s = i >> 11;
    int co = mt * 16 + (l & 15);
    int tap = s * 4 + (l >> 4);
    float v = 0.f;
    if (tap < 27 && j < 4) v = W1[(co * 4 + j) * 27 + tap];
    A[i] = f2bf(v);
}

// ---- pack conv2 weights: [tap][cib][mt][lane][8] ----
__global__ void k_packA2(const float* __restrict__ W2, unsigned short* __restrict__ A) {
    int i = blockIdx.x * 256 + threadIdx.x;
    if (i >= 27 * 2 * 4 * 64 * 8) return;
    int j = i & 7, l = (i >> 3) & 63, mt = (i >> 9) & 3, cib = (i >> 11) & 1, tap = i >> 12;
    int co = mt * 16 + (l & 15);
    int ci = cib * 32 + (l >> 4) * 8 + j;
    A[i] = f2bf(W2[(co * 64 + ci) * 27 + tap]);
}

// ---- pack head weights: k' = d*64+hid; [cib8][mt16][lane][8] ----
__global__ void k_packAh(const float* __restrict__ WH, unsigned short* __restrict__ A) {
    int i = blockIdx.x * 256 + threadIdx.x;
    if (i >= 8 * 16 * 64 * 8) return;
    int j = i & 7, l = (i >> 3) & 63, mt = (i >> 9) & 15, cib = i >> 13;
    int o = mt * 16 + (l & 15);
    int kp = cib * 32 + (l >> 4) * 8 + j;
    int hid = kp & 63, d = kp >> 6;
    A[i] = f2bf(WH[o * 256 + hid * 4 + d]);
}

// ---- conv1 MFMA: grid8 [sp][8ci] -> y1b bf16 [sp][64co] (+bias) ----
// Block: 8h x 8w, 4 waves (one d-plane each). Window [6d][10h][10w][8ci],
// zero-filled halos (incl. d halo) -> no boundary branches in the K loop.
__global__ __launch_bounds__(256) void k_conv1m(const unsigned short* __restrict__ G8,
                                                const unsigned short* __restrict__ A1,
                                                const float* __restrict__ B1,
                                                unsigned short* __restrict__ Y1) {
    __shared__ unsigned short win[600 * 8];   // 9.6 KB
    int bh = blockIdx.x / 25, bw = blockIdx.x % 25;
    int h0 = bh * 8, w0 = bw * 8;
    int t = threadIdx.x;
    for (int e = t; e < 600; e += 256) {
        int p6 = e / 100, rr = e % 100;
        int hh = rr / 10, ww = rr % 10;
        int ps = p6 - 1, hg = h0 + hh - 1, wg = w0 + ww - 1;
        uint4 v = make_uint4(0, 0, 0, 0);
        if ((unsigned)ps < 4u && (unsigned)hg < 200u && (unsigned)wg < 200u)
            v = *reinterpret_cast<const uint4*>(G8 + (size_t)(ps * SP2 + hg * 200 + wg) * 8);
        *reinterpret_cast<uint4*>(win + e * 8) = v;
    }
    __syncthreads();
    int wv = t >> 6, l = t & 63;
    int d = wv, ks = l >> 4, hq = (l >> 3) & 1, wq = l & 7;
    f32x4 acc[4][4] = {};
#pragma unroll
    for (int s = 0; s < 7; ++s) {
        int tap = s * 4 + ks; if (tap > 26) tap = 26;   // A is zero for tap 27
        int kd = tap / 9, r9 = tap % 9, kh = r9 / 3, kw = r9 % 3;
        const uint4* ap = reinterpret_cast<const uint4*>(A1) + (s * 4) * 64 + l;
        short8 afr[4];
#pragma unroll
        for (int mt = 0; mt < 4; ++mt) afr[mt] = __builtin_bit_cast(short8, ap[mt * 64]);
#pragma unroll
        for (int nt = 0; nt < 4; ++nt) {
            int widx = (d + kd) * 100 + (nt * 2 + hq + kh) * 10 + (wq + kw);
            short8 bfr = *reinterpret_cast<const short8*>(win + widx * 8);
#pragma unroll
            for (int mt = 0; mt < 4; ++mt)
                acc[mt][nt] = __builtin_amdgcn_mfma_f32_16x16x32_bf16(afr[mt], bfr, acc[mt][nt], 0, 0, 0);
        }
    }
#pragma unroll
    for (int mt = 0; mt < 4; ++mt) {
        int co0 = mt * 16 + ks * 4;
        float b0 = B1[co0], b1 = B1[co0 + 1], b2 = B1[co0 + 2], b3 = B1[co0 + 3];
#pragma unroll
        for (int nt = 0; nt < 4; ++nt) {
            int sp = d * SP2 + (h0 + nt * 2 + hq) * 200 + (w0 + wq);
            uint2 o;
            o.x = (unsigned)f2bf(acc[mt][nt][0] + b0) | ((unsigned)f2bf(acc[mt][nt][1] + b1) << 16);
            o.y = (unsigned)f2bf(acc[mt][nt][2] + b2) | ((unsigned)f2bf(acc[mt][nt][3] + b3) << 16);
            *reinterpret_cast<uint2*>(Y1 + (size_t)sp * 64 + co0) = o;
        }
    }
}

// ---- conv2 MFMA: X bf16 [sp][64ci] -> Y bf16 [sp][64co] ----
__global__ __launch_bounds__(256) void k_conv2m(const unsigned short* __restrict__ XT,
                                                const unsigned short* __restrict__ A2,
                                                const float* __restrict__ B2,
                                                unsigned short* __restrict__ Y2) {
    __shared__ unsigned short win[400 * 72];
    int bh = blockIdx.x / 25, bw = blockIdx.x % 25;
    int h0 = bh * 8, w0 = bw * 8;
    int t = threadIdx.x;
    for (int e = t; e < 3200; e += 256) {
        int cell = e >> 3, sl = e & 7;
        int p = cell / 100, rr = cell % 100;
        int hh = rr / 10, ww = rr % 10;
        int hg = h0 + hh - 1, wg = w0 + ww - 1;
        uint4 v = make_uint4(0, 0, 0, 0);
        if ((unsigned)hg < 200u && (unsigned)wg < 200u)
            v = *reinterpret_cast<const uint4*>(XT + (size_t)(p * SP2 + hg * 200 + wg) * 64 + sl * 8);
        *reinterpret_cast<uint4*>(win + cell * 72 + sl * 8) = v;
    }
    __syncthreads();
    int wv = t >> 6, l = t & 63;
    int d = wv, ks = l >> 4, hq = (l >> 3) & 1, wq = l & 7;
    f32x4 acc[4][4] = {};
    for (int kd = 0; kd < 3; ++kd) {
        int p = d + kd - 1;
        if ((unsigned)p >= 4u) continue;
#pragma unroll
        for (int khw = 0; khw < 9; ++khw) {
            int kh = khw / 3, kw = khw % 3;
            int tap = kd * 9 + khw;
#pragma unroll
            for (int cib = 0; cib < 2; ++cib) {
                const uint4* ap = reinterpret_cast<const uint4*>(A2) + ((tap * 2 + cib) * 4) * 64 + l;
                short8 afr[4];
#pragma unroll
                for (int mt = 0; mt < 4; ++mt) afr[mt] = __builtin_bit_cast(short8, ap[mt * 64]);
#pragma unroll
                for (int nt = 0; nt < 4; ++nt) {
                    int cell = (p * 10 + nt * 2 + hq + kh) * 10 + (wq + kw);
                    short8 bfr = *reinterpret_cast<const short8*>(win + cell * 72 + cib * 32 + ks * 8);
#pragma unroll
                    for (int mt = 0; mt < 4; ++mt)
                        acc[mt][nt] = __builtin_amdgcn_mfma_f32_16x16x32_bf16(afr[mt], bfr, acc[mt][nt], 0, 0, 0);
                }
            }
        }
    }
#pragma unroll
    for (int mt = 0; mt < 4; ++mt) {
        int co0 = mt * 16 + ks * 4;
        float b0 = B2[co0], b1 = B2[co0 + 1], b2 = B2[co0 + 2], b3 = B2[co0 + 3];
#pragma unroll
        for (int nt = 0; nt < 4; ++nt) {
            int sp = d * SP2 + (h0 + nt * 2 + hq) * 200 + (w0 + wq);
            uint2 o;
            o.x = (unsigned)f2bf(acc[mt][nt][0] + b0) | ((unsigned)f2bf(acc[mt][nt][1] + b1) << 16);
            o.y = (unsigned)f2bf(acc[mt][nt][2] + b2) | ((unsigned)f2bf(acc[mt][nt][3] + b3) << 16);
            *reinterpret_cast<uint2*>(Y2 + (size_t)sp * 64 + co0) = o;
        }
    }
}

// ---- BN stats over bf16 [sp][64]: per-block partials, then finalize ----
__global__ __launch_bounds__(256) void k_stats2p(const unsigned short* __restrict__ Y2,
                                                 float* __restrict__ P) {
    int bid = blockIdx.x, t = threadIdx.x, wv = t >> 6, l = t & 63;
    float s = 0.f, q = 0.f;
    int r0 = bid * 625, r1 = r0 + 625;
    for (int r = r0 + wv; r < r1; r += 4) {
        float v = bf2f(Y2[(size_t)r * 64 + l]);
        s += v; q += v * v;
    }
    __shared__ float ls[4][64], lq[4][64];
    ls[wv][l] = s; lq[wv][l] = q;
    __syncthreads();
    if (t < 64) {
        P[bid * 128 + t]      = ls[0][t] + ls[1][t] + ls[2][t] + ls[3][t];
        P[bid * 128 + 64 + t] = lq[0][t] + lq[1][t] + lq[2][t] + lq[3][t];
    }
}

__global__ void k_stats2f(const float* __restrict__ P, const float* __restrict__ G,
                          const float* __restrict__ BE, float* __restrict__ AB) {
    int c = threadIdx.x;  // 64
    float S = 0.f, Q = 0.f;
    for (int b = 0; b < 256; ++b) { S += P[b * 128 + c]; Q += P[b * 128 + 64 + c]; }
    float m = S * (1.f / SP3), var = Q * (1.f / SP3) - m * m;
    float a = G[c] * rsqrtf(var + EPSF);
    AB[c] = a; AB[64 + c] = BE[c] - m * a;
}

// ---- BN+ReLU in place on bf16 [sp][64] ----
__global__ __launch_bounds__(256) void k_bnrelu2(unsigned short* __restrict__ Y2,
                                                 const float* __restrict__ AB) {
    int i = blockIdx.x * 256 + threadIdx.x;
    int co0 = (i * 8) & 63;
    uint4 v = *reinterpret_cast<uint4*>(Y2 + (size_t)i * 8);
    unsigned r[4]; r[0] = v.x; r[1] = v.y; r[2] = v.z; r[3] = v.w;
#pragma unroll
    for (int k = 0; k < 4; ++k) {
        float lo = bf2f((unsigned short)(r[k] & 0xffff));
        float hi = bf2f((unsigned short)(r[k] >> 16));
        int c = co0 + k * 2;
        lo = fmaxf(fmaf(AB[c], lo, AB[64 + c]), 0.f);
        hi = fmaxf(fmaf(AB[c + 1], hi, AB[64 + c + 1]), 0.f);
        r[k] = (unsigned)f2bf(lo) | ((unsigned)f2bf(hi) << 16);
    }
    v.x = r[0]; v.y = r[1]; v.z = r[2]; v.w = r[3];
    *reinterpret_cast<uint4*>(Y2 + (size_t)i * 8) = v;
}

// ---- head MFMA: y2b [sp][64] (k'=d*64+hid) x AH -> out fp32 [256][40000] ----
__global__ __launch_bounds__(256) void k_headm(const unsigned short* __restrict__ X,
                                               const unsigned short* __restrict__ AH,
                                               const float* __restrict__ BH,
                                               float* __restrict__ O) {
    int s0 = blockIdx.x * 16;
    int t = threadIdx.x, wv = t >> 6, l = t & 63;
    int ks = l >> 4, n = l & 15;
    f32x4 acc[4] = {};
#pragma unroll
    for (int cib = 0; cib < 8; ++cib) {
        int d = cib >> 1, hid0 = (cib & 1) * 32 + ks * 8;
        short8 bfr = *reinterpret_cast<const short8*>(X + (size_t)(d * SP2 + s0 + n) * 64 + hid0);
        const uint4* ap = reinterpret_cast<const uint4*>(AH) + (cib * 16 + wv * 4) * 64 + l;
#pragma unroll
        for (int mtl = 0; mtl < 4; ++mtl) {
            short8 afr = __builtin_bit_cast(short8, ap[mtl * 64]);
            acc[mtl] = __builtin_amdgcn_mfma_f32_16x16x32_bf16(afr, bfr, acc[mtl], 0, 0, 0);
        }
    }
#pragma unroll
    for (int mtl = 0; mtl < 4; ++mtl) {
        int o0 = (wv * 4 + mtl) * 16 + ks * 4;
        int sp = s0 + n;
#pragma unroll
        for (int r = 0; r < 4; ++r)
            O[(size_t)(o0 + r) * SP2 + sp] = acc[mtl][r] + BH[o0 + r];
    }
}

// ---- duplicate batch0 -> batch1 (after headm; batch1 aliases y1b/y2b) ----
__global__ __launch_bounds__(256) void k_dup(float* __restrict__ O) {
    int i = blockIdx.x * 256 + threadIdx.x;
    float4* p = reinterpret_cast<float4*>(O);
    p[OUTC * SP2 / 4 + i] = p[i];
}

extern "C" void kernel_launch(void* const* d_in, const int* in_sizes, int n_in,
                              void* d_out, int out_size, void* d_ws, size_t ws_size,
                              hipStream_t stream) {
    const float* vox = (const float*)d_in[0];
    const int*   idx = (const int*)d_in[1];
    const float* w1  = (const float*)d_in[3];
    const float* b1  = (const float*)d_in[4];
    const float* g1  = (const float*)d_in[5];
    const float* be1 = (const float*)d_in[6];
    const float* w2  = (const float*)d_in[7];
    const float* b2  = (const float*)d_in[8];
    const float* g2  = (const float*)d_in[9];
    const float* be2 = (const float*)d_in[10];
    const float* wh  = (const float*)d_in[11];
    const float* bh  = (const float*)d_in[12];

    float* out = (float*)d_out;
    // ws layout
    unsigned short* grid8 = (unsigned short*)d_ws;          // 1,280,000 bf16 (2.56MB)
    float* ab1  = (float*)(grid8 + 1280000);                // 128 f
    float* ab2  = ab1 + 128;                                // 128 f
    float* part = ab2 + 128;                                // 32768 f
    unsigned short* apack1 = (unsigned short*)(part + 32768);   // 14,336 bf16
    unsigned short* apack2 = apack1 + 14336;                    // 110,592 bf16
    unsigned short* apackh = apack2 + 110592;                   // 65,536 bf16

    unsigned short* y1b = (unsigned short*)(out + 10240000);    // bf16 [160000][64]
    unsigned short* y2b = y1b + 10240000;                       // bf16 [160000][64]

    hipMemsetAsync(grid8, 0, 1280000 * sizeof(unsigned short), stream);
    k_scatter<<<(VN + 255) / 256, 256, 0, stream>>>(vox, idx, grid8);
    k_packA1<<<56, 256, 0, stream>>>(w1, apack1);
    k_packA2<<<432, 256, 0, stream>>>(w2, apack2);
    k_packAh<<<256, 256, 0, stream>>>(wh, apackh);
    k_conv1m<<<625, 256, 0, stream>>>(grid8, apack1, b1, y1b);
    k_stats2p<<<256, 256, 0, stream>>>(y1b, part);
    k_stats2f<<<1, 64, 0, stream>>>(part, g1, be1, ab1);
    k_bnrelu2<<<5000, 256, 0, stream>>>(y1b, ab1);
    k_conv2m<<<625, 256, 0, stream>>>(y1b, apack2, b2, y2b);
    k_stats2p<<<256, 256, 0, stream>>>(y2b, part);
    k_stats2f<<<1, 64, 0, stream>>>(part, g2, be2, ab2);
    k_bnrelu2<<<5000, 256, 0, stream>>>(y2b, ab2);
    k_headm<<<2500, 256, 0, stream>>>(y2b, apackh, bh, out);
    k_dup<<<10000, 256, 0, stream>>>(out);
}

// Round 4
// 208.821 us; speedup vs baseline: 39.9573x; 1.1718x over previous
//
#include <hip/hip_runtime.h>

// VoxelNet MI355X. Batch collapsed to 1 (identical slots; BN stats invariant).
// conv1/conv2/head all bf16 MFMA 32x32x16, fp32 accumulate.
// Activations channel-minor bf16 [sp][C]. BN+ReLU fused into consumers:
//   conv2 applies BN1 while staging LDS; head applies BN2 on its B-loads.
// y1b/y2b live in ws when ws_size permits (head then writes both batches,
// no dup); else they alias d_out's upper half and k_dup runs last.

#define VN   40000
#define CIN  4
#define PN   32
#define SP2  40000
#define SP3  160000
#define HID  64
#define OUTC 256
#define EPSF 1e-5f

typedef __attribute__((ext_vector_type(8)))  short short8;
typedef __attribute__((ext_vector_type(16))) float f32x16;

__device__ inline unsigned short f2bf(float f) {
    unsigned u = __builtin_bit_cast(unsigned, f);
    return (unsigned short)((u + 0x7fffu + ((u >> 16) & 1u)) >> 16);
}
__device__ inline float bf2f(unsigned short h) {
    return __builtin_bit_cast(float, ((unsigned)h) << 16);
}
__device__ inline short8 ld8(const unsigned short* p) {
    return __builtin_bit_cast(short8, *reinterpret_cast<const uint4*>(p));
}

// ---- scatter-mean: one thread per voxel -> grid8 bf16 [sp][8ci] ----
__global__ __launch_bounds__(256) void k_scatter(const float* __restrict__ vox,
                                                 const int* __restrict__ idx,
                                                 unsigned short* __restrict__ G8) {
    int v = blockIdx.x * 256 + threadIdx.x;
    if (v >= VN) return;
    const float4* p = reinterpret_cast<const float4*>(vox + (size_t)v * CIN * PN);
    float m[4];
#pragma unroll
    for (int c = 0; c < 4; ++c) {
        float s = 0.f;
#pragma unroll
        for (int i = 0; i < PN / 4; ++i) {
            float4 q = p[c * (PN / 4) + i];
            s += (q.x + q.y) + (q.z + q.w);
        }
        m[c] = s * (1.f / PN);
    }
    int x = idx[v * 3 + 0], y = idx[v * 3 + 1], z = idx[v * 3 + 2];
    size_t sp = (size_t)z * SP2 + y * 200 + x;
    uint2 o;
    o.x = (unsigned)f2bf(m[0]) | ((unsigned)f2bf(m[1]) << 16);
    o.y = (unsigned)f2bf(m[2]) | ((unsigned)f2bf(m[3]) << 16);
    *reinterpret_cast<uint2*>(G8 + sp * 8) = o;   // ci 4..7 stay zero (memset)
}

// ---- pack conv1 W: [s14][mt2][lane][8]; co=mt*32+(l&31), tap=s*2+(l>>5), ci=j ----
__global__ void k_packA1(const float* __restrict__ W1, unsigned short* __restrict__ A) {
    int i = blockIdx.x * 256 + threadIdx.x;
    if (i >= 14 * 2 * 64 * 8) return;
    int j = i & 7, l = (i >> 3) & 63, mt = (i >> 9) & 1, s = i >> 10;
    int co = mt * 32 + (l & 31);
    int tap = s * 2 + (l >> 5);
    float v = 0.f;
    if (tap < 27 && j < 4) v = W1[(co * 4 + j) * 27 + tap];
    A[i] = f2bf(v);
}

// ---- pack conv2 W: [tap27][cib4][mt2][lane][8]; ci=cib*16+(l>>5)*8+j ----
__global__ void k_packA2(const float* __restrict__ W2, unsigned short* __restrict__ A) {
    int i = blockIdx.x * 256 + threadIdx.x;
    if (i >= 27 * 4 * 2 * 64 * 8) return;
    int j = i & 7, l = (i >> 3) & 63, mt = (i >> 9) & 1, cib = (i >> 10) & 3, tap = i >> 12;
    int co = mt * 32 + (l & 31);
    int ci = cib * 16 + (l >> 5) * 8 + j;
    A[i] = f2bf(W2[(co * 64 + ci) * 27 + tap]);
}

// ---- pack head W: [cib16][mtg8][lane][8]; o=mtg*32+(l&31), k=cib*16+(l>>5)*8+j ----
__global__ void k_packAh(const float* __restrict__ WH, unsigned short* __restrict__ A) {
    int i = blockIdx.x * 256 + threadIdx.x;
    if (i >= 16 * 8 * 64 * 8) return;
    int j = i & 7, l = (i >> 3) & 63, mtg = (i >> 9) & 7, cib = i >> 12;
    int o = mtg * 32 + (l & 31);
    int k = cib * 16 + (l >> 5) * 8 + j;
    int hid = k & 63, d = k >> 6;
    A[i] = f2bf(WH[o * 256 + hid * 4 + d]);
}

// ---- conv1 MFMA 32x32x16: grid8 [sp][8ci] -> y1b bf16 [sp][64co] (+bias) ----
// Block: 4h x 8w x 4d, 2 waves (wave wv: d = wv*2+nt). Window [6p][6h][10w][8ci]
// zero-padded d-halo -> no kd branches. LDS 5.76 KB.
__global__ __launch_bounds__(128) void k_conv1m(const unsigned short* __restrict__ G8,
                                                const unsigned short* __restrict__ A1,
                                                const float* __restrict__ B1,
                                                unsigned short* __restrict__ Y1) {
    __shared__ unsigned short win[360 * 8];
    int bh = blockIdx.x / 25, bw = blockIdx.x % 25;
    int h0 = bh * 4, w0 = bw * 8;
    int t = threadIdx.x;
    for (int e = t; e < 360; e += 128) {
        int p6 = e / 60, rr = e % 60;
        int hh = rr / 10, ww = rr % 10;
        int ps = p6 - 1, hg = h0 + hh - 1, wg = w0 + ww - 1;
        uint4 v = make_uint4(0, 0, 0, 0);
        if ((unsigned)ps < 4u && (unsigned)hg < 200u && (unsigned)wg < 200u)
            v = *reinterpret_cast<const uint4*>(G8 + (size_t)(ps * SP2 + hg * 200 + wg) * 8);
        *reinterpret_cast<uint4*>(win + e * 8) = v;
    }
    __syncthreads();
    int wv = t >> 6, l = t & 63;
    int hi = l >> 5, h_off = (l & 31) >> 3, w = l & 7;
    int d0 = wv * 2;
    f32x16 acc[2][2] = {};   // [mt][nt]
#pragma unroll
    for (int s = 0; s < 14; ++s) {
        int tap = s * 2 + hi; if (tap > 26) tap = 26;   // A zero for tap 27
        int kd = tap / 9, r9 = tap % 9, kh = r9 / 3, kw = r9 % 3;
        const uint4* ap = reinterpret_cast<const uint4*>(A1) + (s * 2) * 64 + l;
        short8 a0 = __builtin_bit_cast(short8, ap[0]);
        short8 a1 = __builtin_bit_cast(short8, ap[64]);
#pragma unroll
        for (int nt = 0; nt < 2; ++nt) {
            int cell = (d0 + nt + kd) * 60 + (h_off + kh) * 10 + (w + kw);
            short8 bfr = ld8(win + cell * 8);
            acc[0][nt] = __builtin_amdgcn_mfma_f32_32x32x16_bf16(a0, bfr, acc[0][nt], 0, 0, 0);
            acc[1][nt] = __builtin_amdgcn_mfma_f32_32x32x16_bf16(a1, bfr, acc[1][nt], 0, 0, 0);
        }
    }
    const float4* Bv = reinterpret_cast<const float4*>(B1);
#pragma unroll
    for (int mt = 0; mt < 2; ++mt) {
#pragma unroll
        for (int nt = 0; nt < 2; ++nt) {
            int sp = (d0 + nt) * SP2 + (h0 + h_off) * 200 + (w0 + w);
#pragma unroll
            for (int rq = 0; rq < 4; ++rq) {
                int co0 = mt * 32 + rq * 8 + hi * 4;
                float4 bb = Bv[co0 >> 2];
                uint2 o;
                o.x = (unsigned)f2bf(acc[mt][nt][rq * 4 + 0] + bb.x) |
                      ((unsigned)f2bf(acc[mt][nt][rq * 4 + 1] + bb.y) << 16);
                o.y = (unsigned)f2bf(acc[mt][nt][rq * 4 + 2] + bb.z) |
                      ((unsigned)f2bf(acc[mt][nt][rq * 4 + 3] + bb.w) << 16);
                *reinterpret_cast<uint2*>(Y1 + (size_t)sp * 64 + co0) = o;
            }
        }
    }
}

// ---- conv2 MFMA 32x32x16: y1b (BN1+ReLU applied on stage) -> y2b (+bias) ----
// Block: 4h x 8w x 4d, 2 waves. Window [4p][6h][10w][64ci], XOR-swizzled 16B
// chunks. LDS 30.72 KB -> 5 blocks/CU.
__global__ __launch_bounds__(128) void k_conv2m(const unsigned short* __restrict__ X,
                                                const unsigned short* __restrict__ A2,
                                                const float* __restrict__ AB1,
                                                const float* __restrict__ B2,
                                                unsigned short* __restrict__ Y2) {
    __shared__ unsigned short win[240 * 64];
    int bh = blockIdx.x / 25, bw = blockIdx.x % 25;
    int h0 = bh * 4, w0 = bw * 8;
    int t = threadIdx.x;
    int s8 = (t & 7) * 8;      // this thread's fixed 8-channel chunk
    float a8[8], b8[8];
#pragma unroll
    for (int j = 0; j < 8; ++j) { a8[j] = AB1[s8 + j]; b8[j] = AB1[64 + s8 + j]; }
#pragma unroll
    for (int i = 0; i < 15; ++i) {
        int cell = i * 16 + (t >> 3);
        int p = cell / 60, rr = cell % 60;
        int hh = rr / 10, ww = rr % 10;
        int hg = h0 + hh - 1, wg = w0 + ww - 1;
        uint2 o = make_uint2(0, 0), o2 = make_uint2(0, 0);
        if ((unsigned)hg < 200u && (unsigned)wg < 200u) {
            uint4 raw = *reinterpret_cast<const uint4*>(X + (size_t)(p * SP2 + hg * 200 + wg) * 64 + s8);
            unsigned r[4] = {raw.x, raw.y, raw.z, raw.w};
            unsigned q[4];
#pragma unroll
            for (int k = 0; k < 4; ++k) {
                float lo = bf2f((unsigned short)(r[k] & 0xffff));
                float hv = bf2f((unsigned short)(r[k] >> 16));
                lo = fmaxf(fmaf(a8[k * 2], lo, b8[k * 2]), 0.f);
                hv = fmaxf(fmaf(a8[k * 2 + 1], hv, b8[k * 2 + 1]), 0.f);
                q[k] = (unsigned)f2bf(lo) | ((unsigned)f2bf(hv) << 16);
            }
            o = make_uint2(q[0], q[1]); o2 = make_uint2(q[2], q[3]);
        }
        int slot = (t & 7) ^ (cell & 7);
        uint4 st = make_uint4(o.x, o.y, o2.x, o2.y);
        *reinterpret_cast<uint4*>(win + cell * 64 + slot * 8) = st;
    }
    __syncthreads();
    int wv = t >> 6, l = t & 63;
    int hi = l >> 5, h_off = (l & 31) >> 3, w = l & 7;
    int d0 = wv * 2;
    f32x16 acc[2][2] = {};   // [mt][nt]
    for (int kd = 0; kd < 3; ++kd) {
        int p0 = d0 + kd - 1;
        bool v0 = (unsigned)p0 < 4u;
        bool v1 = (unsigned)(p0 + 1) < 4u;
#pragma unroll
        for (int khw = 0; khw < 9; ++khw) {
            int kh = khw / 3, kw = khw % 3;
            int tap = kd * 9 + khw;
            int rowc = (h_off + kh) * 10 + (w + kw);
            int cell0 = p0 * 60 + rowc;
            int cell1 = cell0 + 60;
#pragma unroll
            for (int cib = 0; cib < 4; ++cib) {
                const uint4* ap = reinterpret_cast<const uint4*>(A2) + ((tap * 4 + cib) * 2) * 64 + l;
                short8 a0 = __builtin_bit_cast(short8, ap[0]);
                short8 a1 = __builtin_bit_cast(short8, ap[64]);
                int kch = cib * 2 + hi;
                if (v0) {
                    short8 b0 = ld8(win + cell0 * 64 + ((kch ^ (cell0 & 7)) << 3));
                    acc[0][0] = __builtin_amdgcn_mfma_f32_32x32x16_bf16(a0, b0, acc[0][0], 0, 0, 0);
                    acc[1][0] = __builtin_amdgcn_mfma_f32_32x32x16_bf16(a1, b0, acc[1][0], 0, 0, 0);
                }
                if (v1) {
                    short8 b1 = ld8(win + cell1 * 64 + ((kch ^ (cell1 & 7)) << 3));
                    acc[0][1] = __builtin_amdgcn_mfma_f32_32x32x16_bf16(a0, b1, acc[0][1], 0, 0, 0);
                    acc[1][1] = __builtin_amdgcn_mfma_f32_32x32x16_bf16(a1, b1, acc[1][1], 0, 0, 0);
                }
            }
        }
    }
    const float4* Bv = reinterpret_cast<const float4*>(B2);
#pragma unroll
    for (int mt = 0; mt < 2; ++mt) {
#pragma unroll
        for (int nt = 0; nt < 2; ++nt) {
            int sp = (d0 + nt) * SP2 + (h0 + h_off) * 200 + (w0 + w);
#pragma unroll
            for (int rq = 0; rq < 4; ++rq) {
                int co0 = mt * 32 + rq * 8 + hi * 4;
                float4 bb = Bv[co0 >> 2];
                uint2 o;
                o.x = (unsigned)f2bf(acc[mt][nt][rq * 4 + 0] + bb.x) |
                      ((unsigned)f2bf(acc[mt][nt][rq * 4 + 1] + bb.y) << 16);
                o.y = (unsigned)f2bf(acc[mt][nt][rq * 4 + 2] + bb.z) |
                      ((unsigned)f2bf(acc[mt][nt][rq * 4 + 3] + bb.w) << 16);
                *reinterpret_cast<uint2*>(Y2 + (size_t)sp * 64 + co0) = o;
            }
        }
    }
}

// ---- BN stats over bf16 [sp][64] (raw, post-bias): 800 blocks x 200 rows ----
__global__ __launch_bounds__(256) void k_stats2p(const unsigned short* __restrict__ Y,
                                                 float* __restrict__ P) {
    int bid = blockIdx.x, t = threadIdx.x, wv = t >> 6, l = t & 63;
    float s = 0.f, q = 0.f;
    int r0 = bid * 200;
    for (int r = r0 + wv; r < r0 + 200; r += 4) {
        float v = bf2f(Y[(size_t)r * 64 + l]);
        s += v; q += v * v;
    }
    __shared__ float ls[4][64], lq[4][64];
    ls[wv][l] = s; lq[wv][l] = q;
    __syncthreads();
    if (t < 64) {
        P[bid * 128 + t]      = ls[0][t] + ls[1][t] + ls[2][t] + ls[3][t];
        P[bid * 128 + 64 + t] = lq[0][t] + lq[1][t] + lq[2][t] + lq[3][t];
    }
}

__global__ void k_stats2f(const float* __restrict__ P, const float* __restrict__ G,
                          const float* __restrict__ BE, float* __restrict__ AB) {
    int c = threadIdx.x;  // 64
    float S = 0.f, Q = 0.f;
    for (int b = 0; b < 800; ++b) { S += P[b * 128 + c]; Q += P[b * 128 + 64 + c]; }
    float m = S * (1.f / SP3), var = Q * (1.f / SP3) - m * m;
    float a = G[c] * rsqrtf(var + EPSF);
    AB[c] = a; AB[64 + c] = BE[c] - m * a;
}

// ---- head MFMA 32x32x16, BN2+ReLU fused on B-load; optional batch1 write ----
__global__ __launch_bounds__(256) void k_headm(const unsigned short* __restrict__ X,
                                               const unsigned short* __restrict__ AH,
                                               const float* __restrict__ AB2,
                                               const float* __restrict__ BH,
                                               float* __restrict__ O, int dup2) {
    __shared__ float sab[128];
    int t = threadIdx.x;
    if (t < 128) sab[t] = AB2[t];
    __syncthreads();
    int s0 = blockIdx.x * 32;
    int wv = t >> 6, l = t & 63, hi = l >> 5, col = l & 31;
    int sp = s0 + col;
    f32x16 acc[2] = {};
#pragma unroll
    for (int cib = 0; cib < 16; ++cib) {
        int d = cib >> 2, hid0 = (cib & 3) * 16 + hi * 8;
        uint4 raw = *reinterpret_cast<const uint4*>(X + (size_t)(d * SP2 + sp) * 64 + hid0);
        unsigned r[4] = {raw.x, raw.y, raw.z, raw.w};
        unsigned q[4];
#pragma unroll
        for (int k = 0; k < 4; ++k) {
            int c0 = hid0 + k * 2;
            float lo = bf2f((unsigned short)(r[k] & 0xffff));
            float hv = bf2f((unsigned short)(r[k] >> 16));
            lo = fmaxf(fmaf(sab[c0], lo, sab[64 + c0]), 0.f);
            hv = fmaxf(fmaf(sab[c0 + 1], hv, sab[64 + c0 + 1]), 0.f);
            q[k] = (unsigned)f2bf(lo) | ((unsigned)f2bf(hv) << 16);
        }
        short8 bfr = __builtin_bit_cast(short8, make_uint4(q[0], q[1], q[2], q[3]));
#pragma unroll
        for (int mt = 0; mt < 2; ++mt) {
            const uint4* ap = reinterpret_cast<const uint4*>(AH) + ((cib * 8 + wv * 2 + mt)) * 64 + l;
            short8 afr = __builtin_bit_cast(short8, *ap);
            acc[mt] = __builtin_amdgcn_mfma_f32_32x32x16_bf16(afr, bfr, acc[mt], 0, 0, 0);
        }
    }
    const float4* Bv = reinterpret_cast<const float4*>(BH);
#pragma unroll
    for (int mt = 0; mt < 2; ++mt) {
#pragma unroll
        for (int rq = 0; rq < 4; ++rq) {
            int co0 = wv * 64 + mt * 32 + rq * 8 + hi * 4;
            float4 bb = Bv[co0 >> 2];
#pragma unroll
            for (int j = 0; j < 4; ++j) {
                float val = acc[mt][rq * 4 + j] + ((const float*)&bb)[j];
                size_t o = (size_t)(co0 + j) * SP2 + sp;
                O[o] = val;
                if (dup2) O[10240000 + o] = val;
            }
        }
    }
}

// ---- duplicate batch0 -> batch1 (fallback mode only) ----
__global__ __launch_bounds__(256) void k_dup(float* __restrict__ O) {
    int i = blockIdx.x * 256 + threadIdx.x;
    float4* p = reinterpret_cast<float4*>(O);
    p[OUTC * SP2 / 4 + i] = p[i];
}

extern "C" void kernel_launch(void* const* d_in, const int* in_sizes, int n_in,
                              void* d_out, int out_size, void* d_ws, size_t ws_size,
                              hipStream_t stream) {
    const float* vox = (const float*)d_in[0];
    const int*   idx = (const int*)d_in[1];
    const float* w1  = (const float*)d_in[3];
    const float* b1  = (const float*)d_in[4];
    const float* g1  = (const float*)d_in[5];
    const float* be1 = (const float*)d_in[6];
    const float* w2  = (const float*)d_in[7];
    const float* b2  = (const float*)d_in[8];
    const float* g2  = (const float*)d_in[9];
    const float* be2 = (const float*)d_in[10];
    const float* wh  = (const float*)d_in[11];
    const float* bh  = (const float*)d_in[12];

    float* out = (float*)d_out;
    char* ws = (char*)d_ws;
    unsigned short* grid8  = (unsigned short*)ws;                 // 2,560,000 B
    float*          ab1    = (float*)(ws + 2560000);              // 512 B
    float*          ab2    = (float*)(ws + 2560512);              // 512 B
    float*          part   = (float*)(ws + 2561024);              // 409,600 B
    unsigned short* apack1 = (unsigned short*)(ws + 2970624);     // 28,672 B
    unsigned short* apack2 = (unsigned short*)(ws + 2999296);     // 221,184 B
    unsigned short* apackh = (unsigned short*)(ws + 3220480);     // 131,072 B

    bool ws_mode = ws_size >= 44311552u;
    unsigned short* y1b, * y2b;
    if (ws_mode) {
        y1b = (unsigned short*)(ws + 3351552);
        y2b = (unsigned short*)(ws + 23831552);
    } else {
        y1b = (unsigned short*)(out + 10240000);
        y2b = y1b + 10240000;
    }

    hipMemsetAsync(grid8, 0, 2560000, stream);
    k_scatter<<<(VN + 255) / 256, 256, 0, stream>>>(vox, idx, grid8);
    k_packA1<<<56, 256, 0, stream>>>(w1, apack1);
    k_packA2<<<432, 256, 0, stream>>>(w2, apack2);
    k_packAh<<<256, 256, 0, stream>>>(wh, apackh);
    k_conv1m<<<1250, 128, 0, stream>>>(grid8, apack1, b1, y1b);
    k_stats2p<<<800, 256, 0, stream>>>(y1b, part);
    k_stats2f<<<1, 64, 0, stream>>>(part, g1, be1, ab1);
    k_conv2m<<<1250, 128, 0, stream>>>(y1b, apack2, ab1, b2, y2b);
    k_stats2p<<<800, 256, 0, stream>>>(y2b, part);
    k_stats2f<<<1, 64, 0, stream>>>(part, g2, be2, ab2);
    k_headm<<<1250, 256, 0, stream>>>(y2b, apackh, ab2, bh, out, ws_mode ? 1 : 0);
    if (!ws_mode)
        k_dup<<<10000, 256, 0, stream>>>(out);
}